// Round 4
// baseline (2558.027 us; speedup 1.0000x reference)
//
#include <hip/hip_runtime.h>

// PowerWhitening on MI355X (gfx950).
//   k_gram  : G = x^T x partials + column sums (panel-streamed, reg-prefetch)
//   k_cov   : reduce partials -> mu, C = G/N - mu mu^T
//   k_solve : single-workgroup serial deflation solve iterating M2 = C^4
//             (25 dependent steps == 100 C-steps, scale-free / deferred norm).
//             Exact rank-4 M2 maintenance under deflation (v normalized,
//             u=Cv, u2=C^2v, u3=C^3v, a=v.u, e=||Cv||):
//               M2 += -e(u3 v'+v u3') - e(u2 u'+u u2') + e^2(u2 v'+v u2')
//                     + (e^2 a - e^3)(u v'+v u') + e^2 u u' + (2e^4-2e^3 a) v v'
//             W removed from the solve: store s*w (s = rs*e^-1/4) per step,
//             W = V'V rebuilt by k_wbuild.
//   k_out   : out = (x - mu) @ W  (W symmetric), panel GEMM, reg-prefetch,
//             conflict-free transposed x staging (stride 129).
// All kernels keep static LDS <= 35KB.

#define D 128
#define N_ITER 100          // must be divisible by 4 (25 M2-steps)
#define PART_STRIDE 16512   // per-block partial: 16384 G + 128 colsum
#define XS_STRIDE 129       // k_out transposed-tile stride (conflict-free)

// ================================================================ k_gram
__global__ __launch_bounds__(256) void k_gram(const float* __restrict__ x,
                                              float* __restrict__ Gp,
                                              int rows_per_block,
                                              int use_partial) {
  __shared__ __align__(16) float xs[32 * D];    // 16KB panel: 32 rows x 128
  const int t = threadIdx.x;
  const int tx = t & 15, ty = t >> 4;
  float4* xs4 = (float4*)xs;

  float acc[8][8];
#pragma unroll
  for (int i = 0; i < 8; ++i)
#pragma unroll
    for (int j = 0; j < 8; ++j) acc[i][j] = 0.f;
  float csl = 0.f;

  const float4* xg = (const float4*)x;
  const size_t blk_f4 = (size_t)blockIdx.x * rows_per_block * (D / 4);
  const int npanels = rows_per_block / 32;

  float4 pf[4];
#pragma unroll
  for (int i = 0; i < 4; ++i) pf[i] = xg[blk_f4 + t + i * 256];

  for (int p = 0; p < npanels; ++p) {
    __syncthreads();                       // LDS free from previous compute
#pragma unroll
    for (int i = 0; i < 4; ++i) xs4[t + i * 256] = pf[i];
    if (p + 1 < npanels) {
      const size_t nb = blk_f4 + (size_t)(p + 1) * 1024;
#pragma unroll
      for (int i = 0; i < 4; ++i) pf[i] = xg[nb + t + i * 256];
    }
    __syncthreads();                       // panel ready

    if (t < D) {                           // column sums (waves 0-1)
#pragma unroll
      for (int r = 0; r < 32; ++r) csl += xs[r * D + t];
    }
#pragma unroll 4
    for (int r = 0; r < 32; ++r) {
      float4 A0 = xs4[r * 32 + ty];
      float4 A1 = xs4[r * 32 + ty + 16];
      float4 B0 = xs4[r * 32 + tx];
      float4 B1 = xs4[r * 32 + tx + 16];
      float a[8] = {A0.x, A0.y, A0.z, A0.w, A1.x, A1.y, A1.z, A1.w};
      float b[8] = {B0.x, B0.y, B0.z, B0.w, B1.x, B1.y, B1.z, B1.w};
#pragma unroll
      for (int i = 0; i < 8; ++i)
#pragma unroll
        for (int j = 0; j < 8; ++j)
          acc[i][j] = fmaf(a[i], b[j], acc[i][j]);
    }
  }

  // rows {4ty..4ty+3, 64+4ty..}, cols {4tx.., 64+4tx..}
  if (use_partial) {
    float* g = Gp + (size_t)blockIdx.x * PART_STRIDE;
#pragma unroll
    for (int i = 0; i < 8; ++i) {
      const int row = (i < 4) ? (4 * ty + i) : (60 + 4 * ty + i);
      *(float4*)&g[row * D + 4 * tx] =
          make_float4(acc[i][0], acc[i][1], acc[i][2], acc[i][3]);
      *(float4*)&g[row * D + 64 + 4 * tx] =
          make_float4(acc[i][4], acc[i][5], acc[i][6], acc[i][7]);
    }
    if (t < D) g[D * D + t] = csl;
  } else {
#pragma unroll
    for (int i = 0; i < 8; ++i) {
      const int row = (i < 4) ? (4 * ty + i) : (60 + 4 * ty + i);
#pragma unroll
      for (int j = 0; j < 4; ++j) {
        atomicAdd(&Gp[row * D + 4 * tx + j], acc[i][j]);
        atomicAdd(&Gp[row * D + 64 + 4 * tx + j], acc[i][4 + j]);
      }
    }
    if (t < D) atomicAdd(&Gp[D * D + t], csl);
  }
}

// ================================================================ k_cov
__global__ __launch_bounds__(256) void k_cov(const float* __restrict__ Gp, int nparts,
                                             float* __restrict__ C, float* __restrict__ mu,
                                             float inv_n) {
  __shared__ __align__(16) float mus[D];
  const int t = threadIdx.x;
  if (t < D) {
    float s = 0.f;
    for (int b = 0; b < nparts; ++b) s += Gp[(size_t)b * PART_STRIDE + D * D + t];
    float m = s * inv_n;
    mus[t] = m;
    if (blockIdx.x == 0) mu[t] = m;
  }
  __syncthreads();
  const int e = blockIdx.x * 256 + t;   // 64 * 256 = 16384 entries
  float s = 0.f;
#pragma unroll 8
  for (int b = 0; b < nparts; ++b) s += Gp[(size_t)b * PART_STRIDE + e];
  C[e] = s * inv_n - mus[e >> 7] * mus[e & (D - 1)];
}

// ================================================================ k_solve
__device__ __forceinline__ float pair_sum(float p) {
  // add partner lane (lane^1) via DPP quad_perm [1,0,3,2]. fp add is
  // bit-commutative -> both lanes produce identical bits (no LDS race).
  int q = __builtin_amdgcn_mov_dpp(__float_as_int(p), 0xB1, 0xF, 0xF, true);
  return p + __int_as_float(q);
}

__device__ __forceinline__ float matvec_half(const float (&A)[64],
                                             const float* __restrict__ vh) {
  const float4* vv = (const float4*)vh;
  float a0 = 0.f, a1 = 0.f, a2 = 0.f, a3 = 0.f;
  float a4 = 0.f, a5 = 0.f, a6 = 0.f, a7 = 0.f;
#pragma unroll
  for (int j = 0; j < 16; j += 2) {
    float4 u0 = vv[j];
    float4 u1 = vv[j + 1];
    a0 = fmaf(A[4 * j + 0], u0.x, a0);
    a1 = fmaf(A[4 * j + 1], u0.y, a1);
    a2 = fmaf(A[4 * j + 2], u0.z, a2);
    a3 = fmaf(A[4 * j + 3], u0.w, a3);
    a4 = fmaf(A[4 * j + 4], u1.x, a4);
    a5 = fmaf(A[4 * j + 5], u1.y, a5);
    a6 = fmaf(A[4 * j + 6], u1.z, a6);
    a7 = fmaf(A[4 * j + 7], u1.w, a7);
  }
  return ((a0 + a1) + (a2 + a3)) + ((a4 + a5) + (a6 + a7));
}

// 256 threads (4 waves): thread t owns row r = t>>1, column half h = t&1 of
// C (cr[64]) and M2 = C^4 (m2r[64]) in registers. LDS <= 35KB via two-pass
// symmetric staging (C/M symmetric: staged row k serves both the scalar
// A-operand C[r][k] = Cs[k][r] (consecutive-r lanes -> conflict-free) and
// the broadcast B-operand row C[k][h*64..]).
__global__ __launch_bounds__(256, 1) void k_solve(const float* __restrict__ Cg,
                                                  const float* __restrict__ R,
                                                  float* __restrict__ Vout) {
  __shared__ __align__(16) float Cs[64 * D];   // 32KB two-pass staging
  __shared__ __align__(16) float vb[2][D];
  __shared__ __align__(16) float ub[3][D];     // U1, U2, U3 (unnormalized)
  __shared__ float redbuf[12];
  const int t = threadIdx.x;
  const int r = t >> 1;
  const int h = t & 1;
  float4* Cs4 = (float4*)Cs;

  // ---------- prologue: M = C^2 then M2 = M^2 (two-pass each) ----------
  float mr[64], m2r[64];
#pragma unroll
  for (int j = 0; j < 64; ++j) mr[j] = 0.f;

  for (int pass = 0; pass < 2; ++pass) {
    __syncthreads();
#pragma unroll
    for (int i = 0; i < 8; ++i)       // stage C rows [64*pass, 64*pass+64)
      Cs4[t + i * 256] = ((const float4*)Cg)[pass * 2048 + t + i * 256];
    __syncthreads();
#pragma unroll 4
    for (int k = 0; k < 64; ++k) {
      float a = Cs[k * D + r];                      // C[r][64p+k] via symmetry
      const float4* bk = &Cs4[k * 32 + h * 16];
#pragma unroll
      for (int j = 0; j < 16; ++j) {
        float4 u = bk[j];
        mr[4 * j + 0] = fmaf(a, u.x, mr[4 * j + 0]);
        mr[4 * j + 1] = fmaf(a, u.y, mr[4 * j + 1]);
        mr[4 * j + 2] = fmaf(a, u.z, mr[4 * j + 2]);
        mr[4 * j + 3] = fmaf(a, u.w, mr[4 * j + 3]);
      }
    }
  }

#pragma unroll
  for (int j = 0; j < 64; ++j) m2r[j] = 0.f;
  for (int pass = 0; pass < 2; ++pass) {
    __syncthreads();
    if ((r >> 6) == pass) {           // rows [64p, 64p+64) publish M halves
#pragma unroll
      for (int j = 0; j < 16; ++j)
        Cs4[(r & 63) * 32 + h * 16 + j] =
            make_float4(mr[4 * j], mr[4 * j + 1], mr[4 * j + 2], mr[4 * j + 3]);
    }
    __syncthreads();
#pragma unroll 4
    for (int k = 0; k < 64; ++k) {
      float a = Cs[k * D + r];                      // M[r][64p+k] via symmetry
      const float4* bk = &Cs4[k * 32 + h * 16];
#pragma unroll
      for (int j = 0; j < 16; ++j) {
        float4 u = bk[j];
        m2r[4 * j + 0] = fmaf(a, u.x, m2r[4 * j + 0]);
        m2r[4 * j + 1] = fmaf(a, u.y, m2r[4 * j + 1]);
        m2r[4 * j + 2] = fmaf(a, u.z, m2r[4 * j + 2]);
        m2r[4 * j + 3] = fmaf(a, u.w, m2r[4 * j + 3]);
      }
    }
  }

  // load C half-row AFTER the squarings (keeps prologue register peak low)
  float cr[64];
  {
    const float4* Crow = (const float4*)(Cg + r * D + h * 64);
#pragma unroll
    for (int j = 0; j < 16; ++j) ((float4*)cr)[j] = Crow[j];
  }

  float w0 = R[r * D + 0];            // prefetch v0 for outer step 0
  const float* v0h = &vb[0][h * 64];
  const float* v1h = &vb[1][h * 64];

  // ---------------------- 128 deflation steps ----------------------
  for (int i = 0; i < D; ++i) {
    __syncthreads();                  // prev-step vb/ub readers done
    vb[0][r] = w0;
    __syncthreads();
    {                                 // prefetch next v0 (hides L2 latency)
      int inx = (i + 1 < D) ? (i + 1) : i;
      w0 = R[r * D + inx];
    }

    // 25 scale-free M2-steps (w <- M2 w), static ping-pong: 12 x 2 + 1
    float pw;
#pragma unroll 1
    for (int k = 0; k < 12; ++k) {
      pw = pair_sum(matvec_half(m2r, v0h));
      vb[1][r] = pw;
      __syncthreads();
      pw = pair_sum(matvec_half(m2r, v1h));
      vb[0][r] = pw;
      __syncthreads();
    }
    pw = pair_sum(matvec_half(m2r, v0h));
    vb[1][r] = pw;
    __syncthreads();
    // w = vb[1]; pw = w[r].

    // U1 = C w ; overlap ||w||^2 reduction (independent -> same barrier)
    float p1 = pair_sum(matvec_half(cr, v1h));
    ub[0][r] = p1;
    float sw = pw * pw;
#pragma unroll
    for (int m = 1; m < 64; m <<= 1) sw += __shfl_xor(sw, m);
    if ((t & 63) == 0) redbuf[t >> 6] = sw;
    __syncthreads();
    const float Sw = redbuf[0] + redbuf[1] + redbuf[2] + redbuf[3]; // 2||w||^2
    const float rs = rsqrtf(0.5f * Sw);

    // U2 = C U1 ; overlap ||U1||^2 and w.U1 reductions
    float p2 = pair_sum(matvec_half(cr, &ub[0][h * 64]));
    ub[1][r] = p2;
    float su = p1 * p1, al = pw * p1;
#pragma unroll
    for (int m = 1; m < 64; m <<= 1) {
      su += __shfl_xor(su, m);
      al += __shfl_xor(al, m);
    }
    if ((t & 63) == 0) { redbuf[4 + (t >> 6)] = su; redbuf[8 + (t >> 6)] = al; }
    __syncthreads();
    const float Su = redbuf[4] + redbuf[5] + redbuf[6] + redbuf[7];
    const float Al = redbuf[8] + redbuf[9] + redbuf[10] + redbuf[11];
    const float e  = rs * sqrtf(0.5f * Su);     // ||C v||
    const float al_n = rs * rs * 0.5f * Al;     // v.u

    // U3 = C U2
    float p3 = pair_sum(matvec_half(cr, &ub[1][h * 64]));
    ub[2][r] = p3;

    // store scaled eigvec for W = V'V:  s*w, s = rs * e^(-1/4)
    if (h == 0) {
      const float s = rs * rsqrtf(sqrtf(e));
      Vout[i * D + r] = s * pw;
    }
    __syncthreads();                  // ub[2] ready

    // ---- rank-1 C update + rank-4 M2 update (column vecs unnormalized) ----
    const float vr = rs * pw, u1r = rs * p1, u2r = rs * p2, u3r = rs * p3;
    const float e2 = e * e;
    const float beta  = e2 * (al_n - e);              // e^2 a - e^3
    const float gamma = 2.f * e2 * e * (e - al_n);    // 2e^4 - 2e^3 a
    const float Av  = rs * (-e * u3r + e2 * u2r + beta * u1r + gamma * vr);
    const float Au  = rs * (-e * u2r + e2 * u1r + beta * vr);
    const float Au2 = rs * (-e * u1r + e2 * vr);
    const float Au3 = rs * (-e * vr);
    const float cc  = rs * (-e * vr);

    const float4* w4  = (const float4*)(&vb[1][h * 64]);
    const float4* u14 = (const float4*)(&ub[0][h * 64]);
    const float4* u24 = (const float4*)(&ub[1][h * 64]);
    const float4* u34 = (const float4*)(&ub[2][h * 64]);
#pragma unroll
    for (int j = 0; j < 16; ++j) {
      float4 wv = w4[j], a1v = u14[j], a2v = u24[j], a3v = u34[j];
      cr[4 * j + 0] = fmaf(cc, wv.x, cr[4 * j + 0]);
      cr[4 * j + 1] = fmaf(cc, wv.y, cr[4 * j + 1]);
      cr[4 * j + 2] = fmaf(cc, wv.z, cr[4 * j + 2]);
      cr[4 * j + 3] = fmaf(cc, wv.w, cr[4 * j + 3]);
      float m0 = m2r[4 * j + 0], m1 = m2r[4 * j + 1];
      float m2v = m2r[4 * j + 2], m3 = m2r[4 * j + 3];
      m0 = fmaf(Av, wv.x, m0); m0 = fmaf(Au, a1v.x, m0);
      m0 = fmaf(Au2, a2v.x, m0); m0 = fmaf(Au3, a3v.x, m0);
      m1 = fmaf(Av, wv.y, m1); m1 = fmaf(Au, a1v.y, m1);
      m1 = fmaf(Au2, a2v.y, m1); m1 = fmaf(Au3, a3v.y, m1);
      m2v = fmaf(Av, wv.z, m2v); m2v = fmaf(Au, a1v.z, m2v);
      m2v = fmaf(Au2, a2v.z, m2v); m2v = fmaf(Au3, a3v.z, m2v);
      m3 = fmaf(Av, wv.w, m3); m3 = fmaf(Au, a1v.w, m3);
      m3 = fmaf(Au2, a2v.w, m3); m3 = fmaf(Au3, a3v.w, m3);
      m2r[4 * j + 0] = m0; m2r[4 * j + 1] = m1;
      m2r[4 * j + 2] = m2v; m2r[4 * j + 3] = m3;
    }
  }
}

// ================================================================ k_wbuild
// Wt[j][k] = sum_i V[i][j] * V[i][k]   (V rows pre-scaled by e^-1/4)
__global__ __launch_bounds__(256) void k_wbuild(const float* __restrict__ V,
                                                float* __restrict__ Wt) {
  __shared__ __align__(16) float Vs[64 * D];   // 32KB, two passes over i
  const int t = threadIdx.x;
  const int j = blockIdx.x * 32 + (t >> 3);    // 4 blocks x 32 rows
  const int o = t & 7;                         // 16-col octant
  float4* Vs4 = (float4*)Vs;

  float acc[16];
#pragma unroll
  for (int c = 0; c < 16; ++c) acc[c] = 0.f;

  for (int pass = 0; pass < 2; ++pass) {
    __syncthreads();
#pragma unroll
    for (int i = 0; i < 8; ++i)
      Vs4[t + i * 256] = ((const float4*)V)[pass * 2048 + t + i * 256];
    __syncthreads();
#pragma unroll 4
    for (int ii = 0; ii < 64; ++ii) {
      float a = Vs[ii * D + j];
#pragma unroll
      for (int jj = 0; jj < 4; ++jj) {
        float4 b = Vs4[ii * 32 + o * 4 + jj];
        acc[4 * jj + 0] = fmaf(a, b.x, acc[4 * jj + 0]);
        acc[4 * jj + 1] = fmaf(a, b.y, acc[4 * jj + 1]);
        acc[4 * jj + 2] = fmaf(a, b.z, acc[4 * jj + 2]);
        acc[4 * jj + 3] = fmaf(a, b.w, acc[4 * jj + 3]);
      }
    }
  }
#pragma unroll
  for (int jj = 0; jj < 4; ++jj)
    *(float4*)&Wt[j * D + o * 16 + 4 * jj] =
        make_float4(acc[4 * jj], acc[4 * jj + 1], acc[4 * jj + 2], acc[4 * jj + 3]);
}

// ================================================================ k_out
// out = (x - mu) @ W  (W symmetric == W^T). k in 4 panels of 32; x-panel
// stored TRANSPOSED in LDS with stride 129: scatter bank = (4kq+c+row)%32
// -> conflict-free across the wave's 8 rows x 8 kq; row reads land on banks
// {0,8,16,24}+ii -> conflict-free.
__global__ __launch_bounds__(256) void k_out(const float* __restrict__ x,
                                             const float* __restrict__ mu,
                                             const float* __restrict__ Wt,
                                             float* __restrict__ out) {
  __shared__ __align__(16) float xs[32 * XS_STRIDE];  // 16.5KB [k_loc][row]
  __shared__ __align__(16) float ws[32 * D];          // 16KB  [k_loc][col]
  __shared__ __align__(16) float mus[D];
  const int t = threadIdx.x;
  const int tx = t & 15, ty = t >> 4;
  float4* ws4 = (float4*)ws;

  if (t < 32) ((float4*)mus)[t] = ((const float4*)mu)[t];

  const size_t row0 = (size_t)blockIdx.x * D;
  const float4* xg = (const float4*)x;
  const float4* wg = (const float4*)Wt;

  float acc[8][8];
#pragma unroll
  for (int i = 0; i < 8; ++i)
#pragma unroll
    for (int j = 0; j < 8; ++j) acc[i][j] = 0.f;

  // prefetch panel 0
  float4 xpf[4], wpf[4];
#pragma unroll
  for (int i = 0; i < 4; ++i) {
    int idx = t + i * 256;                    // 1024 f4 per panel
    xpf[i] = xg[(row0 + (idx >> 3)) * 32 + (idx & 7)];
    wpf[i] = wg[idx];
  }
  __syncthreads();                            // mus staged

  for (int p = 0; p < 4; ++p) {
#pragma unroll
    for (int i = 0; i < 4; ++i) {
      int idx = t + i * 256;
      int row = idx >> 3, kq = idx & 7;
      float4 m = ((const float4*)mus)[p * 8 + kq];
      float4 u = xpf[i];
      u.x -= m.x; u.y -= m.y; u.z -= m.z; u.w -= m.w;
      xs[(kq * 4 + 0) * XS_STRIDE + row] = u.x;   // transposed scatter
      xs[(kq * 4 + 1) * XS_STRIDE + row] = u.y;
      xs[(kq * 4 + 2) * XS_STRIDE + row] = u.z;
      xs[(kq * 4 + 3) * XS_STRIDE + row] = u.w;
      ws4[idx] = wpf[i];
    }
    if (p + 1 < 4) {
#pragma unroll
      for (int i = 0; i < 4; ++i) {
        int idx = t + i * 256;
        xpf[i] = xg[(row0 + (idx >> 3)) * 32 + (p + 1) * 8 + (idx & 7)];
        wpf[i] = wg[(p + 1) * 1024 + idx];
      }
    }
    __syncthreads();                          // panel ready

#pragma unroll 4
    for (int k = 0; k < 32; ++k) {
      float a[8];
#pragma unroll
      for (int ii = 0; ii < 8; ++ii) a[ii] = xs[k * XS_STRIDE + ty * 8 + ii];
      float4 B0 = ws4[k * 32 + tx];
      float4 B1 = ws4[k * 32 + tx + 16];
      float b[8] = {B0.x, B0.y, B0.z, B0.w, B1.x, B1.y, B1.z, B1.w};
#pragma unroll
      for (int ii = 0; ii < 8; ++ii)
#pragma unroll
        for (int jj = 0; jj < 8; ++jj)
          acc[ii][jj] = fmaf(a[ii], b[jj], acc[ii][jj]);
    }
    __syncthreads();                          // compute done, LDS reusable
  }

#pragma unroll
  for (int ii = 0; ii < 8; ++ii) {
    size_t ro = (row0 + ty * 8 + ii) * D;
    *(float4*)(out + ro + 4 * tx) =
        make_float4(acc[ii][0], acc[ii][1], acc[ii][2], acc[ii][3]);
    *(float4*)(out + ro + 64 + 4 * tx) =
        make_float4(acc[ii][4], acc[ii][5], acc[ii][6], acc[ii][7]);
  }
}

// ================================================================ launch
extern "C" void kernel_launch(void* const* d_in, const int* in_sizes, int n_in,
                              void* d_out, int out_size, void* d_ws, size_t ws_size,
                              hipStream_t stream) {
  const float* x = (const float*)d_in[0];
  const float* R = (const float*)d_in[1];
  float* out = (float*)d_out;
  const int N = in_sizes[0] / D;                 // 524288

  const size_t tail = (size_t)(3 * D * D + D);   // C, mu, V, Wt
  int gblk, nparts, use_partial;
  if (ws_size >= ((size_t)512 * PART_STRIDE + tail) * sizeof(float)) {
    gblk = 512; nparts = 512; use_partial = 1;   // 2 blocks/CU
  } else if (ws_size >= ((size_t)256 * PART_STRIDE + tail) * sizeof(float)) {
    gblk = 256; nparts = 256; use_partial = 1;
  } else {
    gblk = 256; nparts = 1; use_partial = 0;     // atomic fallback
  }
  const size_t gp_elems = (size_t)(use_partial ? nparts : 1) * PART_STRIDE;

  float* Gp = (float*)d_ws;
  float* C  = Gp + gp_elems;
  float* mu = C + D * D;
  float* V  = mu + D;
  float* Wt = V + D * D;

  if (!use_partial)
    hipMemsetAsync(d_ws, 0, PART_STRIDE * sizeof(float), stream);

  k_gram<<<gblk, 256, 0, stream>>>(x, Gp, N / gblk, use_partial);
  k_cov<<<64, 256, 0, stream>>>(Gp, nparts, C, mu, 1.0f / (float)N);
  k_solve<<<1, 256, 0, stream>>>(C, R, V);
  k_wbuild<<<4, 256, 0, stream>>>(V, Wt);
  k_out<<<N / D, 256, 0, stream>>>(x, mu, Wt, out);
}

// Round 5
// 2533.124 us; speedup vs baseline: 1.0098x; 1.0098x over previous
//
#include <hip/hip_runtime.h>

// PowerWhitening on MI355X (gfx950).
//   k_gram  : G = x^T x partials + column sums (panel-streamed, reg-prefetch)
//   k_cov   : reduce partials -> mu, C = G/N - mu mu^T
//   k_solve : single-workgroup serial deflation solve iterating M2 = C^4
//             (25 dependent steps == 100 C-steps, scale-free / deferred norm).
//             Register arrays are float4-typed with static member access ONLY
//             (no reinterpret casts on locals): round-4 counters proved the
//             casts blocked SROA -> 192-float arrays spilled to scratch
//             (VGPR_Count=100, FETCH_SIZE=79MB, 1051 cy/iter).
//   k_out   : out = (x - mu) @ W  (W symmetric), panel GEMM, reg-prefetch,
//             conflict-free transposed x staging (stride 129).

#define D 128
#define N_ITER 100          // must be divisible by 4 (25 M2-steps)
#define PART_STRIDE 16512   // per-block partial: 16384 G + 128 colsum
#define XS_STRIDE 129       // k_out transposed-tile stride (conflict-free)

// ================================================================ k_gram
__global__ __launch_bounds__(256) void k_gram(const float* __restrict__ x,
                                              float* __restrict__ Gp,
                                              int rows_per_block,
                                              int use_partial) {
  __shared__ __align__(16) float xs[32 * D];    // 16KB panel: 32 rows x 128
  const int t = threadIdx.x;
  const int tx = t & 15, ty = t >> 4;
  float4* xs4 = (float4*)xs;

  float acc[8][8];
#pragma unroll
  for (int i = 0; i < 8; ++i)
#pragma unroll
    for (int j = 0; j < 8; ++j) acc[i][j] = 0.f;
  float csl = 0.f;

  const float4* xg = (const float4*)x;
  const size_t blk_f4 = (size_t)blockIdx.x * rows_per_block * (D / 4);
  const int npanels = rows_per_block / 32;

  float4 pf[4];
#pragma unroll
  for (int i = 0; i < 4; ++i) pf[i] = xg[blk_f4 + t + i * 256];

  for (int p = 0; p < npanels; ++p) {
    __syncthreads();                       // LDS free from previous compute
#pragma unroll
    for (int i = 0; i < 4; ++i) xs4[t + i * 256] = pf[i];
    if (p + 1 < npanels) {
      const size_t nb = blk_f4 + (size_t)(p + 1) * 1024;
#pragma unroll
      for (int i = 0; i < 4; ++i) pf[i] = xg[nb + t + i * 256];
    }
    __syncthreads();                       // panel ready

    if (t < D) {                           // column sums (waves 0-1)
#pragma unroll
      for (int r = 0; r < 32; ++r) csl += xs[r * D + t];
    }
#pragma unroll 4
    for (int r = 0; r < 32; ++r) {
      float4 A0 = xs4[r * 32 + ty];
      float4 A1 = xs4[r * 32 + ty + 16];
      float4 B0 = xs4[r * 32 + tx];
      float4 B1 = xs4[r * 32 + tx + 16];
      float a[8] = {A0.x, A0.y, A0.z, A0.w, A1.x, A1.y, A1.z, A1.w};
      float b[8] = {B0.x, B0.y, B0.z, B0.w, B1.x, B1.y, B1.z, B1.w};
#pragma unroll
      for (int i = 0; i < 8; ++i)
#pragma unroll
        for (int j = 0; j < 8; ++j)
          acc[i][j] = fmaf(a[i], b[j], acc[i][j]);
    }
  }

  // rows {4ty..4ty+3, 64+4ty..}, cols {4tx.., 64+4tx..}
  if (use_partial) {
    float* g = Gp + (size_t)blockIdx.x * PART_STRIDE;
#pragma unroll
    for (int i = 0; i < 8; ++i) {
      const int row = (i < 4) ? (4 * ty + i) : (60 + 4 * ty + i);
      *(float4*)&g[row * D + 4 * tx] =
          make_float4(acc[i][0], acc[i][1], acc[i][2], acc[i][3]);
      *(float4*)&g[row * D + 64 + 4 * tx] =
          make_float4(acc[i][4], acc[i][5], acc[i][6], acc[i][7]);
    }
    if (t < D) g[D * D + t] = csl;
  } else {
#pragma unroll
    for (int i = 0; i < 8; ++i) {
      const int row = (i < 4) ? (4 * ty + i) : (60 + 4 * ty + i);
#pragma unroll
      for (int j = 0; j < 4; ++j) {
        atomicAdd(&Gp[row * D + 4 * tx + j], acc[i][j]);
        atomicAdd(&Gp[row * D + 64 + 4 * tx + j], acc[i][4 + j]);
      }
    }
    if (t < D) atomicAdd(&Gp[D * D + t], csl);
  }
}

// ================================================================ k_cov
__global__ __launch_bounds__(256) void k_cov(const float* __restrict__ Gp, int nparts,
                                             float* __restrict__ C, float* __restrict__ mu,
                                             float inv_n) {
  __shared__ __align__(16) float mus[D];
  const int t = threadIdx.x;
  if (t < D) {
    float s = 0.f;
    for (int b = 0; b < nparts; ++b) s += Gp[(size_t)b * PART_STRIDE + D * D + t];
    float m = s * inv_n;
    mus[t] = m;
    if (blockIdx.x == 0) mu[t] = m;
  }
  __syncthreads();
  const int e = blockIdx.x * 256 + t;   // 64 * 256 = 16384 entries
  float s = 0.f;
#pragma unroll 8
  for (int b = 0; b < nparts; ++b) s += Gp[(size_t)b * PART_STRIDE + e];
  C[e] = s * inv_n - mus[e >> 7] * mus[e & (D - 1)];
}

// ================================================================ k_solve
__device__ __forceinline__ float pair_sum(float p) {
  // add partner lane (lane^1) via DPP quad_perm [1,0,3,2]. fp add is
  // bit-commutative -> both lanes produce identical bits (no LDS race).
  int q = __builtin_amdgcn_mov_dpp(__float_as_int(p), 0xB1, 0xF, 0xF, true);
  return p + __int_as_float(q);
}

// A is a float4-typed register array (static member access only -> SROA keeps
// it in VGPRs). vv is an LDS pointer (ds_read_b128 broadcasts).
__device__ __forceinline__ float matvec_half(const float4 (&A)[16],
                                             const float4* __restrict__ vv) {
  float a0 = 0.f, a1 = 0.f, a2 = 0.f, a3 = 0.f;
  float a4 = 0.f, a5 = 0.f, a6 = 0.f, a7 = 0.f;
#pragma unroll
  for (int j = 0; j < 16; j += 2) {
    float4 u0 = vv[j];
    float4 u1 = vv[j + 1];
    a0 = fmaf(A[j].x, u0.x, a0);
    a1 = fmaf(A[j].y, u0.y, a1);
    a2 = fmaf(A[j].z, u0.z, a2);
    a3 = fmaf(A[j].w, u0.w, a3);
    a4 = fmaf(A[j + 1].x, u1.x, a4);
    a5 = fmaf(A[j + 1].y, u1.y, a5);
    a6 = fmaf(A[j + 1].z, u1.z, a6);
    a7 = fmaf(A[j + 1].w, u1.w, a7);
  }
  return ((a0 + a1) + (a2 + a3)) + ((a4 + a5) + (a6 + a7));
}

// 256 threads (4 waves): thread t owns row r = t>>1, column half h = t&1 of
// C (cr[16] float4) and M2 = C^4 (m2r[16] float4) in registers. LDS <= 35KB
// via two-pass symmetric staging (C/M symmetric: staged row k serves both the
// scalar A-operand C[r][k] = Cs[k][r] and the broadcast B-operand row).
__global__ __launch_bounds__(256, 1) void k_solve(const float* __restrict__ Cg,
                                                  const float* __restrict__ R,
                                                  float* __restrict__ Vout) {
  __shared__ __align__(16) float Cs[64 * D];   // 32KB two-pass staging
  __shared__ __align__(16) float vb[2][D];
  __shared__ __align__(16) float ub[3][D];     // U1, U2, U3 (unnormalized)
  __shared__ float redbuf[12];
  const int t = threadIdx.x;
  const int r = t >> 1;
  const int h = t & 1;
  float4* Cs4 = (float4*)Cs;

  // ---------- prologue: M = C^2 then M2 = M^2 (two-pass each) ----------
  float4 mr[16], m2r[16];
#pragma unroll
  for (int j = 0; j < 16; ++j) mr[j] = make_float4(0.f, 0.f, 0.f, 0.f);

  for (int pass = 0; pass < 2; ++pass) {
    __syncthreads();
#pragma unroll
    for (int i = 0; i < 8; ++i)       // stage C rows [64*pass, 64*pass+64)
      Cs4[t + i * 256] = ((const float4*)Cg)[pass * 2048 + t + i * 256];
    __syncthreads();
#pragma unroll 4
    for (int k = 0; k < 64; ++k) {
      float a = Cs[k * D + r];                      // C[r][64p+k] via symmetry
      const float4* bk = &Cs4[k * 32 + h * 16];
#pragma unroll
      for (int j = 0; j < 16; ++j) {
        float4 u = bk[j];
        mr[j].x = fmaf(a, u.x, mr[j].x);
        mr[j].y = fmaf(a, u.y, mr[j].y);
        mr[j].z = fmaf(a, u.z, mr[j].z);
        mr[j].w = fmaf(a, u.w, mr[j].w);
      }
    }
  }

#pragma unroll
  for (int j = 0; j < 16; ++j) m2r[j] = make_float4(0.f, 0.f, 0.f, 0.f);
  for (int pass = 0; pass < 2; ++pass) {
    __syncthreads();
    if ((r >> 6) == pass) {           // rows [64p, 64p+64) publish M halves
#pragma unroll
      for (int j = 0; j < 16; ++j)
        Cs4[(r & 63) * 32 + h * 16 + j] = mr[j];
    }
    __syncthreads();
#pragma unroll 4
    for (int k = 0; k < 64; ++k) {
      float a = Cs[k * D + r];                      // M[r][64p+k] via symmetry
      const float4* bk = &Cs4[k * 32 + h * 16];
#pragma unroll
      for (int j = 0; j < 16; ++j) {
        float4 u = bk[j];
        m2r[j].x = fmaf(a, u.x, m2r[j].x);
        m2r[j].y = fmaf(a, u.y, m2r[j].y);
        m2r[j].z = fmaf(a, u.z, m2r[j].z);
        m2r[j].w = fmaf(a, u.w, m2r[j].w);
      }
    }
  }

  // load C half-row AFTER the squarings (keeps prologue register peak low)
  float4 cr[16];
  {
    const float4* Crow = (const float4*)(Cg + r * D + h * 64);
#pragma unroll
    for (int j = 0; j < 16; ++j) cr[j] = Crow[j];
  }

  float w0 = R[r * D + 0];            // prefetch v0 for outer step 0
  const float4* v0h = (const float4*)(&vb[0][h * 64]);
  const float4* v1h = (const float4*)(&vb[1][h * 64]);

  // ---------------------- 128 deflation steps ----------------------
  for (int i = 0; i < D; ++i) {
    __syncthreads();                  // prev-step vb/ub readers done
    vb[0][r] = w0;
    __syncthreads();
    {                                 // prefetch next v0 (hides L2 latency)
      int inx = (i + 1 < D) ? (i + 1) : i;
      w0 = R[r * D + inx];
    }

    // 25 scale-free M2-steps (w <- M2 w), static ping-pong: 12 x 2 + 1
    float pw;
#pragma unroll 1
    for (int k = 0; k < 12; ++k) {
      pw = pair_sum(matvec_half(m2r, v0h));
      vb[1][r] = pw;
      __syncthreads();
      pw = pair_sum(matvec_half(m2r, v1h));
      vb[0][r] = pw;
      __syncthreads();
    }
    pw = pair_sum(matvec_half(m2r, v0h));
    vb[1][r] = pw;
    __syncthreads();
    // w = vb[1]; pw = w[r].

    // U1 = C w ; overlap ||w||^2 reduction (independent -> same barrier)
    float p1 = pair_sum(matvec_half(cr, v1h));
    ub[0][r] = p1;
    float sw = pw * pw;
#pragma unroll
    for (int m = 1; m < 64; m <<= 1) sw += __shfl_xor(sw, m);
    if ((t & 63) == 0) redbuf[t >> 6] = sw;
    __syncthreads();
    const float Sw = redbuf[0] + redbuf[1] + redbuf[2] + redbuf[3]; // 2||w||^2
    const float rs = rsqrtf(0.5f * Sw);

    // U2 = C U1 ; overlap ||U1||^2 and w.U1 reductions
    float p2 = pair_sum(matvec_half(cr, (const float4*)(&ub[0][h * 64])));
    ub[1][r] = p2;
    float su = p1 * p1, al = pw * p1;
#pragma unroll
    for (int m = 1; m < 64; m <<= 1) {
      su += __shfl_xor(su, m);
      al += __shfl_xor(al, m);
    }
    if ((t & 63) == 0) { redbuf[4 + (t >> 6)] = su; redbuf[8 + (t >> 6)] = al; }
    __syncthreads();
    const float Su = redbuf[4] + redbuf[5] + redbuf[6] + redbuf[7];
    const float Al = redbuf[8] + redbuf[9] + redbuf[10] + redbuf[11];
    const float e  = rs * sqrtf(0.5f * Su);     // ||C v||
    const float al_n = rs * rs * 0.5f * Al;     // v.u

    // U3 = C U2
    float p3 = pair_sum(matvec_half(cr, (const float4*)(&ub[1][h * 64])));
    ub[2][r] = p3;

    // store scaled eigvec for W = V'V:  s*w, s = rs * e^(-1/4)
    if (h == 0) {
      const float s = rs * rsqrtf(sqrtf(e));
      Vout[i * D + r] = s * pw;
    }
    __syncthreads();                  // ub[2] ready

    // ---- rank-1 C update + rank-4 M2 update (column vecs unnormalized) ----
    const float vr = rs * pw, u1r = rs * p1, u2r = rs * p2, u3r = rs * p3;
    const float e2 = e * e;
    const float beta  = e2 * (al_n - e);              // e^2 a - e^3
    const float gamma = 2.f * e2 * e * (e - al_n);    // 2e^4 - 2e^3 a
    const float Av  = rs * (-e * u3r + e2 * u2r + beta * u1r + gamma * vr);
    const float Au  = rs * (-e * u2r + e2 * u1r + beta * vr);
    const float Au2 = rs * (-e * u1r + e2 * vr);
    const float Au3 = rs * (-e * vr);
    const float cc  = rs * (-e * vr);

    const float4* w4  = (const float4*)(&vb[1][h * 64]);
    const float4* u14 = (const float4*)(&ub[0][h * 64]);
    const float4* u24 = (const float4*)(&ub[1][h * 64]);
    const float4* u34 = (const float4*)(&ub[2][h * 64]);
#pragma unroll
    for (int j = 0; j < 16; ++j) {
      float4 wv = w4[j], a1v = u14[j], a2v = u24[j], a3v = u34[j];
      float4 c = cr[j];
      c.x = fmaf(cc, wv.x, c.x);
      c.y = fmaf(cc, wv.y, c.y);
      c.z = fmaf(cc, wv.z, c.z);
      c.w = fmaf(cc, wv.w, c.w);
      cr[j] = c;
      float4 m = m2r[j];
      m.x = fmaf(Av, wv.x, m.x); m.x = fmaf(Au, a1v.x, m.x);
      m.x = fmaf(Au2, a2v.x, m.x); m.x = fmaf(Au3, a3v.x, m.x);
      m.y = fmaf(Av, wv.y, m.y); m.y = fmaf(Au, a1v.y, m.y);
      m.y = fmaf(Au2, a2v.y, m.y); m.y = fmaf(Au3, a3v.y, m.y);
      m.z = fmaf(Av, wv.z, m.z); m.z = fmaf(Au, a1v.z, m.z);
      m.z = fmaf(Au2, a2v.z, m.z); m.z = fmaf(Au3, a3v.z, m.z);
      m.w = fmaf(Av, wv.w, m.w); m.w = fmaf(Au, a1v.w, m.w);
      m.w = fmaf(Au2, a2v.w, m.w); m.w = fmaf(Au3, a3v.w, m.w);
      m2r[j] = m;
    }
  }
}

// ================================================================ k_wbuild
// Wt[j][k] = sum_i V[i][j] * V[i][k]   (V rows pre-scaled by e^-1/4)
__global__ __launch_bounds__(256) void k_wbuild(const float* __restrict__ V,
                                                float* __restrict__ Wt) {
  __shared__ __align__(16) float Vs[64 * D];   // 32KB, two passes over i
  const int t = threadIdx.x;
  const int j = blockIdx.x * 32 + (t >> 3);    // 4 blocks x 32 rows
  const int o = t & 7;                         // 16-col octant
  float4* Vs4 = (float4*)Vs;

  float acc[16];
#pragma unroll
  for (int c = 0; c < 16; ++c) acc[c] = 0.f;

  for (int pass = 0; pass < 2; ++pass) {
    __syncthreads();
#pragma unroll
    for (int i = 0; i < 8; ++i)
      Vs4[t + i * 256] = ((const float4*)V)[pass * 2048 + t + i * 256];
    __syncthreads();
#pragma unroll 4
    for (int ii = 0; ii < 64; ++ii) {
      float a = Vs[ii * D + j];
#pragma unroll
      for (int jj = 0; jj < 4; ++jj) {
        float4 b = Vs4[ii * 32 + o * 4 + jj];
        acc[4 * jj + 0] = fmaf(a, b.x, acc[4 * jj + 0]);
        acc[4 * jj + 1] = fmaf(a, b.y, acc[4 * jj + 1]);
        acc[4 * jj + 2] = fmaf(a, b.z, acc[4 * jj + 2]);
        acc[4 * jj + 3] = fmaf(a, b.w, acc[4 * jj + 3]);
      }
    }
  }
#pragma unroll
  for (int jj = 0; jj < 4; ++jj)
    *(float4*)&Wt[j * D + o * 16 + 4 * jj] =
        make_float4(acc[4 * jj], acc[4 * jj + 1], acc[4 * jj + 2], acc[4 * jj + 3]);
}

// ================================================================ k_out
// out = (x - mu) @ W  (W symmetric == W^T). k in 4 panels of 32; x-panel
// stored TRANSPOSED in LDS with stride 129: scatter bank = (4kq+c+row)%32
// -> conflict-free across the wave's 8 rows x 8 kq; row reads land on banks
// {0,8,16,24}+ii -> conflict-free.
__global__ __launch_bounds__(256) void k_out(const float* __restrict__ x,
                                             const float* __restrict__ mu,
                                             const float* __restrict__ Wt,
                                             float* __restrict__ out) {
  __shared__ __align__(16) float xs[32 * XS_STRIDE];  // 16.5KB [k_loc][row]
  __shared__ __align__(16) float ws[32 * D];          // 16KB  [k_loc][col]
  __shared__ __align__(16) float mus[D];
  const int t = threadIdx.x;
  const int tx = t & 15, ty = t >> 4;
  float4* ws4 = (float4*)ws;

  if (t < 32) ((float4*)mus)[t] = ((const float4*)mu)[t];

  const size_t row0 = (size_t)blockIdx.x * D;
  const float4* xg = (const float4*)x;
  const float4* wg = (const float4*)Wt;

  float acc[8][8];
#pragma unroll
  for (int i = 0; i < 8; ++i)
#pragma unroll
    for (int j = 0; j < 8; ++j) acc[i][j] = 0.f;

  // prefetch panel 0
  float4 xpf[4], wpf[4];
#pragma unroll
  for (int i = 0; i < 4; ++i) {
    int idx = t + i * 256;                    // 1024 f4 per panel
    xpf[i] = xg[(row0 + (idx >> 3)) * 32 + (idx & 7)];
    wpf[i] = wg[idx];
  }
  __syncthreads();                            // mus staged

  for (int p = 0; p < 4; ++p) {
#pragma unroll
    for (int i = 0; i < 4; ++i) {
      int idx = t + i * 256;
      int row = idx >> 3, kq = idx & 7;
      float4 m = ((const float4*)mus)[p * 8 + kq];
      float4 u = xpf[i];
      u.x -= m.x; u.y -= m.y; u.z -= m.z; u.w -= m.w;
      xs[(kq * 4 + 0) * XS_STRIDE + row] = u.x;   // transposed scatter
      xs[(kq * 4 + 1) * XS_STRIDE + row] = u.y;
      xs[(kq * 4 + 2) * XS_STRIDE + row] = u.z;
      xs[(kq * 4 + 3) * XS_STRIDE + row] = u.w;
      ws4[idx] = wpf[i];
    }
    if (p + 1 < 4) {
#pragma unroll
      for (int i = 0; i < 4; ++i) {
        int idx = t + i * 256;
        xpf[i] = xg[(row0 + (idx >> 3)) * 32 + (p + 1) * 8 + (idx & 7)];
        wpf[i] = wg[(p + 1) * 1024 + idx];
      }
    }
    __syncthreads();                          // panel ready

#pragma unroll 4
    for (int k = 0; k < 32; ++k) {
      float a[8];
#pragma unroll
      for (int ii = 0; ii < 8; ++ii) a[ii] = xs[k * XS_STRIDE + ty * 8 + ii];
      float4 B0 = ws4[k * 32 + tx];
      float4 B1 = ws4[k * 32 + tx + 16];
      float b[8] = {B0.x, B0.y, B0.z, B0.w, B1.x, B1.y, B1.z, B1.w};
#pragma unroll
      for (int ii = 0; ii < 8; ++ii)
#pragma unroll
        for (int jj = 0; jj < 8; ++jj)
          acc[ii][jj] = fmaf(a[ii], b[jj], acc[ii][jj]);
    }
    __syncthreads();                          // compute done, LDS reusable
  }

#pragma unroll
  for (int ii = 0; ii < 8; ++ii) {
    size_t ro = (row0 + ty * 8 + ii) * D;
    *(float4*)(out + ro + 4 * tx) =
        make_float4(acc[ii][0], acc[ii][1], acc[ii][2], acc[ii][3]);
    *(float4*)(out + ro + 64 + 4 * tx) =
        make_float4(acc[ii][4], acc[ii][5], acc[ii][6], acc[ii][7]);
  }
}

// ================================================================ launch
extern "C" void kernel_launch(void* const* d_in, const int* in_sizes, int n_in,
                              void* d_out, int out_size, void* d_ws, size_t ws_size,
                              hipStream_t stream) {
  const float* x = (const float*)d_in[0];
  const float* R = (const float*)d_in[1];
  float* out = (float*)d_out;
  const int N = in_sizes[0] / D;                 // 524288

  const size_t tail = (size_t)(3 * D * D + D);   // C, mu, V, Wt
  int gblk, nparts, use_partial;
  if (ws_size >= ((size_t)512 * PART_STRIDE + tail) * sizeof(float)) {
    gblk = 512; nparts = 512; use_partial = 1;   // 2 blocks/CU
  } else if (ws_size >= ((size_t)256 * PART_STRIDE + tail) * sizeof(float)) {
    gblk = 256; nparts = 256; use_partial = 1;
  } else {
    gblk = 256; nparts = 1; use_partial = 0;     // atomic fallback
  }
  const size_t gp_elems = (size_t)(use_partial ? nparts : 1) * PART_STRIDE;

  float* Gp = (float*)d_ws;
  float* C  = Gp + gp_elems;
  float* mu = C + D * D;
  float* V  = mu + D;
  float* Wt = V + D * D;

  if (!use_partial)
    hipMemsetAsync(d_ws, 0, PART_STRIDE * sizeof(float), stream);

  k_gram<<<gblk, 256, 0, stream>>>(x, Gp, N / gblk, use_partial);
  k_cov<<<64, 256, 0, stream>>>(Gp, nparts, C, mu, 1.0f / (float)N);
  k_solve<<<1, 256, 0, stream>>>(C, R, V);
  k_wbuild<<<4, 256, 0, stream>>>(V, Wt);
  k_out<<<N / D, 256, 0, stream>>>(x, mu, Wt, out);
}

// Round 7
// 1996.221 us; speedup vs baseline: 1.2814x; 1.2690x over previous
//
#include <hip/hip_runtime.h>

// PowerWhitening on MI355X (gfx950).
//   k_gram  : G = x^T x partials + column sums (panel-streamed, reg-prefetch)
//   k_cov   : reduce partials -> mu, C = G/N - mu mu^T
//   k_solve : single-workgroup serial deflation solve iterating M2 = C^4
//             (25 dependent steps == 100 C-steps, scale-free / deferred norm).
//             512 threads: thread owns QUARTER-row (r=t>>2, q=t&3) ->
//             64 scalars of matrix state/thread (r4/r5 had 128+ and the
//             allocator spilled at VGPR=100: FETCH 76MB, 1055 cy/iter).
//             Vector buffers quarter-strided by 40 floats: quarter bases on
//             banks {0,8,16,24} -> the 4 distinct ds_read_b128 addresses per
//             instruction are bank-disjoint (was a 4-way conflict at stride 32).
//   k_out   : out = (x - mu) @ W  (W symmetric), panel GEMM, reg-prefetch,
//             conflict-free transposed x staging (stride 129).

#define D 128
#define N_ITER 100          // must be divisible by 4 (25 M2-steps)
#define PART_STRIDE 16512   // per-block partial: 16384 G + 128 colsum
#define XS_STRIDE 129       // k_out transposed-tile stride (conflict-free)
#define VSTRIDE 40          // k_solve vector quarter stride (16B-aligned, +8 banks)

// ================================================================ k_gram
__global__ __launch_bounds__(256) void k_gram(const float* __restrict__ x,
                                              float* __restrict__ Gp,
                                              int rows_per_block,
                                              int use_partial) {
  __shared__ __align__(16) float xs[32 * D];    // 16KB panel: 32 rows x 128
  const int t = threadIdx.x;
  const int tx = t & 15, ty = t >> 4;
  float4* xs4 = (float4*)xs;

  float acc[8][8];
#pragma unroll
  for (int i = 0; i < 8; ++i)
#pragma unroll
    for (int j = 0; j < 8; ++j) acc[i][j] = 0.f;
  float csl = 0.f;

  const float4* xg = (const float4*)x;
  const size_t blk_f4 = (size_t)blockIdx.x * rows_per_block * (D / 4);
  const int npanels = rows_per_block / 32;

  float4 pf[4];
#pragma unroll
  for (int i = 0; i < 4; ++i) pf[i] = xg[blk_f4 + t + i * 256];

  for (int p = 0; p < npanels; ++p) {
    __syncthreads();                       // LDS free from previous compute
#pragma unroll
    for (int i = 0; i < 4; ++i) xs4[t + i * 256] = pf[i];
    if (p + 1 < npanels) {
      const size_t nb = blk_f4 + (size_t)(p + 1) * 1024;
#pragma unroll
      for (int i = 0; i < 4; ++i) pf[i] = xg[nb + t + i * 256];
    }
    __syncthreads();                       // panel ready

    if (t < D) {                           // column sums (waves 0-1)
#pragma unroll
      for (int r = 0; r < 32; ++r) csl += xs[r * D + t];
    }
#pragma unroll 4
    for (int r = 0; r < 32; ++r) {
      float4 A0 = xs4[r * 32 + ty];
      float4 A1 = xs4[r * 32 + ty + 16];
      float4 B0 = xs4[r * 32 + tx];
      float4 B1 = xs4[r * 32 + tx + 16];
      float a[8] = {A0.x, A0.y, A0.z, A0.w, A1.x, A1.y, A1.z, A1.w};
      float b[8] = {B0.x, B0.y, B0.z, B0.w, B1.x, B1.y, B1.z, B1.w};
#pragma unroll
      for (int i = 0; i < 8; ++i)
#pragma unroll
        for (int j = 0; j < 8; ++j)
          acc[i][j] = fmaf(a[i], b[j], acc[i][j]);
    }
  }

  // rows {4ty..4ty+3, 64+4ty..}, cols {4tx.., 64+4tx..}
  if (use_partial) {
    float* g = Gp + (size_t)blockIdx.x * PART_STRIDE;
#pragma unroll
    for (int i = 0; i < 8; ++i) {
      const int row = (i < 4) ? (4 * ty + i) : (60 + 4 * ty + i);
      *(float4*)&g[row * D + 4 * tx] =
          make_float4(acc[i][0], acc[i][1], acc[i][2], acc[i][3]);
      *(float4*)&g[row * D + 64 + 4 * tx] =
          make_float4(acc[i][4], acc[i][5], acc[i][6], acc[i][7]);
    }
    if (t < D) g[D * D + t] = csl;
  } else {
#pragma unroll
    for (int i = 0; i < 8; ++i) {
      const int row = (i < 4) ? (4 * ty + i) : (60 + 4 * ty + i);
#pragma unroll
      for (int j = 0; j < 4; ++j) {
        atomicAdd(&Gp[row * D + 4 * tx + j], acc[i][j]);
        atomicAdd(&Gp[row * D + 64 + 4 * tx + j], acc[i][4 + j]);
      }
    }
    if (t < D) atomicAdd(&Gp[D * D + t], csl);
  }
}

// ================================================================ k_cov
__global__ __launch_bounds__(256) void k_cov(const float* __restrict__ Gp, int nparts,
                                             float* __restrict__ C, float* __restrict__ mu,
                                             float inv_n) {
  __shared__ __align__(16) float mus[D];
  const int t = threadIdx.x;
  if (t < D) {
    float s = 0.f;
    for (int b = 0; b < nparts; ++b) s += Gp[(size_t)b * PART_STRIDE + D * D + t];
    float m = s * inv_n;
    mus[t] = m;
    if (blockIdx.x == 0) mu[t] = m;
  }
  __syncthreads();
  const int e = blockIdx.x * 256 + t;   // 64 * 256 = 16384 entries
  float s = 0.f;
#pragma unroll 8
  for (int b = 0; b < nparts; ++b) s += Gp[(size_t)b * PART_STRIDE + e];
  C[e] = s * inv_n - mus[e >> 7] * mus[e & (D - 1)];
}

// ================================================================ k_solve
// sum over the 4 lanes of a quad (lane^1 then lane^2 DPP quad_perms).
__device__ __forceinline__ float quad_sum(float p) {
  int a = __builtin_amdgcn_mov_dpp(__float_as_int(p), 0xB1, 0xF, 0xF, true); // [1,0,3,2]
  p += __int_as_float(a);
  int b = __builtin_amdgcn_mov_dpp(__float_as_int(p), 0x4E, 0xF, 0xF, true); // [2,3,0,1]
  p += __int_as_float(b);
  return p;
}

// quarter-row dot: A = 8 x float4 register state, vv = LDS float4 pointer.
#define QDOT(A, vv, outv)                                                    \
  {                                                                          \
    float s0 = 0.f, s1 = 0.f, s2 = 0.f, s3 = 0.f;                            \
    _Pragma("unroll") for (int j_ = 0; j_ < 8; ++j_) {                       \
      float4 u_ = (vv)[j_];                                                  \
      s0 = fmaf((A)[j_].x, u_.x, s0);                                        \
      s1 = fmaf((A)[j_].y, u_.y, s1);                                        \
      s2 = fmaf((A)[j_].z, u_.z, s2);                                        \
      s3 = fmaf((A)[j_].w, u_.w, s3);                                        \
    }                                                                        \
    outv = (s0 + s1) + (s2 + s3);                                            \
  }

// 512 threads (8 waves, 2/SIMD): thread t owns row r=t>>2, quarter q=t&3 of
// C (cr[8] f4) and M2=C^4 (m2r[8] f4): 64 scalars of matrix state.
// Vector buffers: vbuf[0,1]=w ping-pong, vbuf[2,3,4]=U1,U2,U3; element k of a
// vector lives at vbuf[b][(k>>5)*VSTRIDE + (k&31)].
__global__ __launch_bounds__(512, 2) void k_solve(const float* __restrict__ Cg,
                                                  const float* __restrict__ R,
                                                  float* __restrict__ Vout) {
  __shared__ __align__(16) float Cs[64 * D];       // 32KB two-pass staging
  __shared__ __align__(16) float vbuf[5][4 * VSTRIDE];
  __shared__ float redbuf[24];
  const int t = threadIdx.x;
  const int r = t >> 2;            // row 0..127
  const int q = t & 3;             // quarter 0..3
  float4* Cs4 = (float4*)Cs;

  // ---------- prologue: M = C^2 then M2 = M^2 (two-pass each) ----------
  float4 mr[8], m2r[8];
#pragma unroll
  for (int j = 0; j < 8; ++j) mr[j] = make_float4(0.f, 0.f, 0.f, 0.f);

  for (int pass = 0; pass < 2; ++pass) {
    __syncthreads();
#pragma unroll
    for (int i = 0; i < 4; ++i)       // stage C rows [64*pass, 64*pass+64)
      Cs4[t + i * 512] = ((const float4*)Cg)[pass * 2048 + t + i * 512];
    __syncthreads();
#pragma unroll 4
    for (int k = 0; k < 64; ++k) {
      float a = Cs[k * D + r];                      // C[r][64p+k] via symmetry
      const float4* bk = &Cs4[k * 32 + q * 8];
#pragma unroll
      for (int j = 0; j < 8; ++j) {
        float4 u = bk[j];
        mr[j].x = fmaf(a, u.x, mr[j].x);
        mr[j].y = fmaf(a, u.y, mr[j].y);
        mr[j].z = fmaf(a, u.z, mr[j].z);
        mr[j].w = fmaf(a, u.w, mr[j].w);
      }
    }
  }

#pragma unroll
  for (int j = 0; j < 8; ++j) m2r[j] = make_float4(0.f, 0.f, 0.f, 0.f);
  for (int pass = 0; pass < 2; ++pass) {
    __syncthreads();
    if ((r >> 6) == pass) {           // rows [64p, 64p+64) publish M quarters
#pragma unroll
      for (int j = 0; j < 8; ++j)
        Cs4[(r & 63) * 32 + q * 8 + j] = mr[j];
    }
    __syncthreads();
#pragma unroll 4
    for (int k = 0; k < 64; ++k) {
      float a = Cs[k * D + r];                      // M[r][64p+k] via symmetry
      const float4* bk = &Cs4[k * 32 + q * 8];
#pragma unroll
      for (int j = 0; j < 8; ++j) {
        float4 u = bk[j];
        m2r[j].x = fmaf(a, u.x, m2r[j].x);
        m2r[j].y = fmaf(a, u.y, m2r[j].y);
        m2r[j].z = fmaf(a, u.z, m2r[j].z);
        m2r[j].w = fmaf(a, u.w, m2r[j].w);
      }
    }
  }

  // load C quarter-row AFTER the squarings (mr dead -> low register peak)
  float4 cr[8];
  {
    const float4* Crow = (const float4*)(Cg + r * D + q * 32);
#pragma unroll
    for (int j = 0; j < 8; ++j) cr[j] = Crow[j];
  }

  float w0 = R[r * D + 0];            // prefetch v0 for outer step 0
  const int wq = ((r >> 5) * VSTRIDE) + (r & 31);   // write slot for element r
  const float4* v0q = (const float4*)(&vbuf[0][q * VSTRIDE]);
  const float4* v1q = (const float4*)(&vbuf[1][q * VSTRIDE]);
  const float4* u0q = (const float4*)(&vbuf[2][q * VSTRIDE]);
  const float4* u1q = (const float4*)(&vbuf[3][q * VSTRIDE]);
  const float4* u2q = (const float4*)(&vbuf[4][q * VSTRIDE]);
  const int wv = t >> 6;              // wave id 0..7

  // ---------------------- 128 deflation steps ----------------------
  for (int i = 0; i < D; ++i) {
    __syncthreads();                  // prev-step vbuf readers done
    if (q == 0) vbuf[0][wq] = w0;
    __syncthreads();
    {                                 // prefetch next v0 (hides L2 latency)
      int inx = (i + 1 < D) ? (i + 1) : i;
      w0 = R[r * D + inx];
    }

    // 25 scale-free M2-steps (w <- M2 w), static ping-pong: 12 x 2 + 1
    float pw, s;
#pragma unroll 1
    for (int k = 0; k < 12; ++k) {
      QDOT(m2r, v0q, s);
      pw = quad_sum(s);
      if (q == 0) vbuf[1][wq] = pw;
      __syncthreads();
      QDOT(m2r, v1q, s);
      pw = quad_sum(s);
      if (q == 0) vbuf[0][wq] = pw;
      __syncthreads();
    }
    QDOT(m2r, v0q, s);
    pw = quad_sum(s);
    if (q == 0) vbuf[1][wq] = pw;
    __syncthreads();
    // w = vbuf[1]; pw = w[r] (duplicated x4 across the quad).

    // U1 = C w ; overlap ||w||^2 reduction (independent -> same barrier)
    QDOT(cr, v1q, s);
    float p1 = quad_sum(s);
    if (q == 0) vbuf[2][wq] = p1;
    float sw = pw * pw;               // each row counted 4x; cancels via /4
#pragma unroll
    for (int m = 1; m < 64; m <<= 1) sw += __shfl_xor(sw, m);
    if ((t & 63) == 0) redbuf[wv] = sw;
    __syncthreads();
    float Sw = 0.f;
#pragma unroll
    for (int m = 0; m < 8; ++m) Sw += redbuf[m];        // 4||w||^2
    const float rs = rsqrtf(0.25f * Sw);

    // U2 = C U1 ; overlap ||U1||^2 and w.U1 reductions
    QDOT(cr, u0q, s);
    float p2 = quad_sum(s);
    if (q == 0) vbuf[3][wq] = p2;
    float su = p1 * p1, al = pw * p1;
#pragma unroll
    for (int m = 1; m < 64; m <<= 1) {
      su += __shfl_xor(su, m);
      al += __shfl_xor(al, m);
    }
    if ((t & 63) == 0) { redbuf[8 + wv] = su; redbuf[16 + wv] = al; }
    __syncthreads();
    float Su = 0.f, Al = 0.f;
#pragma unroll
    for (int m = 0; m < 8; ++m) { Su += redbuf[8 + m]; Al += redbuf[16 + m]; }
    const float e  = rs * sqrtf(0.25f * Su);     // ||C v||
    const float al_n = rs * rs * 0.25f * Al;     // v.u

    // U3 = C U2
    QDOT(cr, u1q, s);
    float p3 = quad_sum(s);
    if (q == 0) vbuf[4][wq] = p3;

    // store scaled eigvec for W = V'V:  sc*w, sc = rs * e^(-1/4)
    if (q == 0) {
      const float sc = rs * rsqrtf(sqrtf(e));
      Vout[i * D + r] = sc * pw;
    }
    __syncthreads();                  // U3 ready

    // ---- rank-1 C update + rank-4 M2 update (column vecs unnormalized) ----
    const float vr = rs * pw, u1r = rs * p1, u2r = rs * p2, u3r = rs * p3;
    const float e2 = e * e;
    const float beta  = e2 * (al_n - e);              // e^2 a - e^3
    const float gamma = 2.f * e2 * e * (e - al_n);    // 2e^4 - 2e^3 a
    const float Av  = rs * (-e * u3r + e2 * u2r + beta * u1r + gamma * vr);
    const float Au  = rs * (-e * u2r + e2 * u1r + beta * vr);
    const float Au2 = rs * (-e * u1r + e2 * vr);
    const float Au3 = rs * (-e * vr);
    const float cc  = rs * (-e * vr);

#pragma unroll
    for (int j = 0; j < 8; ++j) {
      float4 wvv = v1q[j], a1v = u0q[j], a2v = u1q[j], a3v = u2q[j];
      float4 c = cr[j];
      c.x = fmaf(cc, wvv.x, c.x);
      c.y = fmaf(cc, wvv.y, c.y);
      c.z = fmaf(cc, wvv.z, c.z);
      c.w = fmaf(cc, wvv.w, c.w);
      cr[j] = c;
      float4 m = m2r[j];
      m.x = fmaf(Av, wvv.x, m.x); m.x = fmaf(Au, a1v.x, m.x);
      m.x = fmaf(Au2, a2v.x, m.x); m.x = fmaf(Au3, a3v.x, m.x);
      m.y = fmaf(Av, wvv.y, m.y); m.y = fmaf(Au, a1v.y, m.y);
      m.y = fmaf(Au2, a2v.y, m.y); m.y = fmaf(Au3, a3v.y, m.y);
      m.z = fmaf(Av, wvv.z, m.z); m.z = fmaf(Au, a1v.z, m.z);
      m.z = fmaf(Au2, a2v.z, m.z); m.z = fmaf(Au3, a3v.z, m.z);
      m.w = fmaf(Av, wvv.w, m.w); m.w = fmaf(Au, a1v.w, m.w);
      m.w = fmaf(Au2, a2v.w, m.w); m.w = fmaf(Au3, a3v.w, m.w);
      m2r[j] = m;
    }
  }
}

// ================================================================ k_wbuild
// Wt[j][k] = sum_i V[i][j] * V[i][k]   (V rows pre-scaled by e^-1/4)
__global__ __launch_bounds__(256) void k_wbuild(const float* __restrict__ V,
                                                float* __restrict__ Wt) {
  __shared__ __align__(16) float Vs[64 * D];   // 32KB, two passes over i
  const int t = threadIdx.x;
  const int j = blockIdx.x * 32 + (t >> 3);    // 4 blocks x 32 rows
  const int o = t & 7;                         // 16-col octant
  float4* Vs4 = (float4*)Vs;

  float acc[16];
#pragma unroll
  for (int c = 0; c < 16; ++c) acc[c] = 0.f;

  for (int pass = 0; pass < 2; ++pass) {
    __syncthreads();
#pragma unroll
    for (int i = 0; i < 8; ++i)
      Vs4[t + i * 256] = ((const float4*)V)[pass * 2048 + t + i * 256];
    __syncthreads();
#pragma unroll 4
    for (int ii = 0; ii < 64; ++ii) {
      float a = Vs[ii * D + j];
#pragma unroll
      for (int jj = 0; jj < 4; ++jj) {
        float4 b = Vs4[ii * 32 + o * 4 + jj];
        acc[4 * jj + 0] = fmaf(a, b.x, acc[4 * jj + 0]);
        acc[4 * jj + 1] = fmaf(a, b.y, acc[4 * jj + 1]);
        acc[4 * jj + 2] = fmaf(a, b.z, acc[4 * jj + 2]);
        acc[4 * jj + 3] = fmaf(a, b.w, acc[4 * jj + 3]);
      }
    }
  }
#pragma unroll
  for (int jj = 0; jj < 4; ++jj)
    *(float4*)&Wt[j * D + o * 16 + 4 * jj] =
        make_float4(acc[4 * jj], acc[4 * jj + 1], acc[4 * jj + 2], acc[4 * jj + 3]);
}

// ================================================================ k_out
// out = (x - mu) @ W  (W symmetric == W^T). k in 4 panels of 32; x-panel
// stored TRANSPOSED in LDS with stride 129 (conflict-free scatter + reads).
__global__ __launch_bounds__(256) void k_out(const float* __restrict__ x,
                                             const float* __restrict__ mu,
                                             const float* __restrict__ Wt,
                                             float* __restrict__ out) {
  __shared__ __align__(16) float xs[32 * XS_STRIDE];  // 16.5KB [k_loc][row]
  __shared__ __align__(16) float ws[32 * D];          // 16KB  [k_loc][col]
  __shared__ __align__(16) float mus[D];
  const int t = threadIdx.x;
  const int tx = t & 15, ty = t >> 4;
  float4* ws4 = (float4*)ws;

  if (t < 32) ((float4*)mus)[t] = ((const float4*)mu)[t];

  const size_t row0 = (size_t)blockIdx.x * D;
  const float4* xg = (const float4*)x;
  const float4* wg = (const float4*)Wt;

  float acc[8][8];
#pragma unroll
  for (int i = 0; i < 8; ++i)
#pragma unroll
    for (int j = 0; j < 8; ++j) acc[i][j] = 0.f;

  // prefetch panel 0
  float4 xpf[4], wpf[4];
#pragma unroll
  for (int i = 0; i < 4; ++i) {
    int idx = t + i * 256;                    // 1024 f4 per panel
    xpf[i] = xg[(row0 + (idx >> 3)) * 32 + (idx & 7)];
    wpf[i] = wg[idx];
  }
  __syncthreads();                            // mus staged

  for (int p = 0; p < 4; ++p) {
#pragma unroll
    for (int i = 0; i < 4; ++i) {
      int idx = t + i * 256;
      int row = idx >> 3, kq = idx & 7;
      float4 m = ((const float4*)mus)[p * 8 + kq];
      float4 u = xpf[i];
      u.x -= m.x; u.y -= m.y; u.z -= m.z; u.w -= m.w;
      xs[(kq * 4 + 0) * XS_STRIDE + row] = u.x;   // transposed scatter
      xs[(kq * 4 + 1) * XS_STRIDE + row] = u.y;
      xs[(kq * 4 + 2) * XS_STRIDE + row] = u.z;
      xs[(kq * 4 + 3) * XS_STRIDE + row] = u.w;
      ws4[idx] = wpf[i];
    }
    if (p + 1 < 4) {
#pragma unroll
      for (int i = 0; i < 4; ++i) {
        int idx = t + i * 256;
        xpf[i] = xg[(row0 + (idx >> 3)) * 32 + (p + 1) * 8 + (idx & 7)];
        wpf[i] = wg[(p + 1) * 1024 + idx];
      }
    }
    __syncthreads();                          // panel ready

#pragma unroll 4
    for (int k = 0; k < 32; ++k) {
      float a[8];
#pragma unroll
      for (int ii = 0; ii < 8; ++ii) a[ii] = xs[k * XS_STRIDE + ty * 8 + ii];
      float4 B0 = ws4[k * 32 + tx];
      float4 B1 = ws4[k * 32 + tx + 16];
      float b[8] = {B0.x, B0.y, B0.z, B0.w, B1.x, B1.y, B1.z, B1.w};
#pragma unroll
      for (int ii = 0; ii < 8; ++ii)
#pragma unroll
        for (int jj = 0; jj < 8; ++jj)
          acc[ii][jj] = fmaf(a[ii], b[jj], acc[ii][jj]);
    }
    __syncthreads();                          // compute done, LDS reusable
  }

#pragma unroll
  for (int ii = 0; ii < 8; ++ii) {
    size_t ro = (row0 + ty * 8 + ii) * D;
    *(float4*)(out + ro + 4 * tx) =
        make_float4(acc[ii][0], acc[ii][1], acc[ii][2], acc[ii][3]);
    *(float4*)(out + ro + 64 + 4 * tx) =
        make_float4(acc[ii][4], acc[ii][5], acc[ii][6], acc[ii][7]);
  }
}

// ================================================================ launch
extern "C" void kernel_launch(void* const* d_in, const int* in_sizes, int n_in,
                              void* d_out, int out_size, void* d_ws, size_t ws_size,
                              hipStream_t stream) {
  const float* x = (const float*)d_in[0];
  const float* R = (const float*)d_in[1];
  float* out = (float*)d_out;
  const int N = in_sizes[0] / D;                 // 524288

  const size_t tail = (size_t)(3 * D * D + D);   // C, mu, V, Wt
  int gblk, nparts, use_partial;
  if (ws_size >= ((size_t)512 * PART_STRIDE + tail) * sizeof(float)) {
    gblk = 512; nparts = 512; use_partial = 1;   // 2 blocks/CU
  } else if (ws_size >= ((size_t)256 * PART_STRIDE + tail) * sizeof(float)) {
    gblk = 256; nparts = 256; use_partial = 1;
  } else {
    gblk = 256; nparts = 1; use_partial = 0;     // atomic fallback
  }
  const size_t gp_elems = (size_t)(use_partial ? nparts : 1) * PART_STRIDE;

  float* Gp = (float*)d_ws;
  float* C  = Gp + gp_elems;
  float* mu = C + D * D;
  float* V  = mu + D;
  float* Wt = V + D * D;

  if (!use_partial)
    hipMemsetAsync(d_ws, 0, PART_STRIDE * sizeof(float), stream);

  k_gram<<<gblk, 256, 0, stream>>>(x, Gp, N / gblk, use_partial);
  k_cov<<<64, 256, 0, stream>>>(Gp, nparts, C, mu, 1.0f / (float)N);
  k_solve<<<1, 512, 0, stream>>>(C, R, V);
  k_wbuild<<<4, 256, 0, stream>>>(V, Wt);
  k_out<<<N / D, 256, 0, stream>>>(x, mu, Wt, out);
}